// Round 14
// baseline (362.482 us; speedup 1.0000x reference)
//
#include <hip/hip_runtime.h>
#include <math.h>

// Zero-padded symmetric weight tables (fp32, kernarg): per sigma,
// [8 zeros][w[R],...,w[1],w[0],w[1],...,w[R]][8 zeros]  (length 2R+17).
// Truncation (renormalized): sigma1 R4 / sigma2 R9 tails ~1e-6;
// sigma4 R12 tail ~0.17% (cancels in cs/lc ratios); sigma8 R16 exact.
struct GW { float w[171]; };
constexpr int W05 = 0;    // sigma 0.5, R=2
constexpr int W1  = 21;   // sigma 1,   R=4
constexpr int W2  = 46;   // sigma 2,   R=9
constexpr int W4  = 81;   // sigma 4,   R=12
constexpr int W8  = 122;  // sigma 8,   R=16

namespace {

constexpr float kC1 = 1e-4f;
constexpr float kC2 = 9e-4f;

// 512 threads/block, 32x32 output tile. LDS = hb only (32.3 KB) -> 4 blocks/CU.
// h-pass reads img1/img2 rows DIRECTLY from global (coalesced, L2-served);
// s=x+y, d=x-y computed on the fly. No input tiles in LDS at all.
//  hb : [<=64 rows][32 slots] float4 (s,d,s2,d2), slot c^((c>>3)&3), 32 KB.
//  L1 reuse of hb: [64][32] floats, plain layout (8 KB).

__device__ __forceinline__ float4 ld4_guard(const float* __restrict__ row, int cx) {
  // Column-guarded float4 load (edge blocks only).
  if (cx >= 0 && cx + 3 < 512) return *reinterpret_cast<const float4*>(row + cx);
  float4 v = make_float4(0.f, 0.f, 0.f, 0.f);
  float* vp = reinterpret_cast<float*>(&v);
#pragma unroll
  for (int u = 0; u < 4; ++u) {
    const int x = cx + u;
    if (x >= 0 && x < 512) vp[u] = row[x];
  }
  return v;
}

// Horizontal pass from GLOBAL, rows trimmed to NROWS=32+2R. One entry/thread.
template<int R, int WOFF, bool EX>
__device__ __forceinline__ void hpass_g(const GW& g, const float* __restrict__ p1,
                                        const float* __restrict__ p2,
                                        float4* __restrict__ hb, int t,
                                        int gx0, int gy0) {
  constexpr int NROWS = 32 + 2 * R;
  constexpr int NE = NROWS * 8;
  constexpr int QS = (16 - R) & ~3;
  constexpr int NG = ((19 + R - QS) >> 2) + 1;
  if (t >= NE) return;
  const int hrow = t >> 3;
  const int cg = t & 7;
  const int gy = gy0 + hrow + (16 - R);
  float a0[4] = {0.f, 0.f, 0.f, 0.f}, a1[4] = {0.f, 0.f, 0.f, 0.f};
  float a2[4] = {0.f, 0.f, 0.f, 0.f}, a3[4] = {0.f, 0.f, 0.f, 0.f};
  if (gy >= 0 && gy < 512) {
    const float* __restrict__ r1 = p1 + ((size_t)gy << 9);
    const float* __restrict__ r2 = p2 + ((size_t)gy << 9);
    const int c0 = gx0 + ((cg + (QS >> 2)) << 2);
#pragma unroll 2
    for (int j = 0; j < NG; ++j) {
      const int cx = c0 + (j << 2);
      float4 a, bb;
      if constexpr (EX) { a = ld4_guard(r1, cx); bb = ld4_guard(r2, cx); }
      else { a = *reinterpret_cast<const float4*>(r1 + cx);
             bb = *reinterpret_cast<const float4*>(r2 + cx); }
      const int wb = WOFF + 8 + QS - 16 + R + 4 * j;  // + u - o; pads absorb
      const float* ap = reinterpret_cast<const float*>(&a);
      const float* bp = reinterpret_cast<const float*>(&bb);
#pragma unroll
      for (int u = 0; u < 4; ++u) {
        const float sv = ap[u] + bp[u];
        const float dv = ap[u] - bp[u];
        const float s2 = sv * sv, d2 = dv * dv;
#pragma unroll
        for (int o = 0; o < 4; ++o) {
          const float wk = g.w[wb + u - o];
          a0[o] += wk * sv; a1[o] += wk * dv;
          a2[o] += wk * s2; a3[o] += wk * d2;
        }
      }
    }
  }
  const int rb = hrow << 5;
#pragma unroll
  for (int o = 0; o < 4; ++o) {
    const int c = (cg << 2) + o;
    hb[rb + (c ^ ((c >> 3) & 3))] = make_float4(a0[o], a1[o], a2[o], a3[o]);
  }
}

// Vertical pass (unchanged from champion). Thread owns col vc, rows vr0..vr0+1.
template<int R, int WOFF>
__device__ __forceinline__ void vpass4(const GW& g, const float4* __restrict__ hb,
                                       int vc, int vr0,
                                       float (&o0)[2], float (&o1)[2],
                                       float (&o2)[2], float (&o3)[2]) {
#pragma unroll
  for (int i = 0; i < 2; ++i) { o0[i] = o1[i] = o2[i] = o3[i] = 0.f; }
  const int fc = vc ^ ((vc >> 3) & 3);
  const float4* __restrict__ hbp = hb + (vr0 << 5) + fc;
#pragma unroll 4
  for (int jj = 0; jj < 2 * R + 2; ++jj) {
    const float4 v = hbp[jj << 5];
    const int wb = WOFF + 8 + jj;
#pragma unroll
    for (int i = 0; i < 2; ++i) {
      const float wk = g.w[wb - i];
      o0[i] += wk * v.x; o1[i] += wk * v.y;
      o2[i] += wk * v.z; o3[i] += wk * v.w;
    }
  }
}

template<int R, int WOFF, int MULT, bool DOLM, bool EX>
__device__ __forceinline__ void sweep4(const GW& g, const float* p1, const float* p2,
                                       float4* hb, int t, int vc, int vr0,
                                       int gx0, int gy0,
                                       float (&PI)[2], float (&lM)[2]) {
  __syncthreads();                  // prior v-reads of hb done
  hpass_g<R, WOFF, EX>(g, p1, p2, hb, t, gx0, gy0);
  __syncthreads();
  float os[2], od[2], os2[2], od2[2];
  vpass4<R, WOFF>(g, hb, vc, vr0, os, od, os2, od2);
#pragma unroll
  for (int i = 0; i < 2; ++i) {
    const float vs = os2[i] - os[i] * os[i];   // Var(x+y)
    const float vd = od2[i] - od[i] * od[i];   // Var(x-y)
    const float cs = (0.5f * (vs - vd) + kC2) / (0.5f * (vs + vd) + kC2);
    float p = cs;
    if constexpr (MULT > 1) p *= cs;
    if constexpr (MULT > 2) p *= cs;
    PI[i] *= p;
    if constexpr (DOLM) {
      const float sa = os[i] * os[i], sb = od[i] * od[i];
      const float lc = (0.5f * (sa - sb) + kC1) / (0.5f * (sa + sb) + kC1);
      lM[i] = lc * lc * lc;
    }
  }
}

// Fused L1 (sigma 8, R=16): h-pass reads all 3 channels of both images from
// global, blurs sum_ch |x-y| (linearity of conv); then v-pass. hbl = hb alias.
template<int R, int WOFF, bool EX>
__device__ __forceinline__ void sweepL1_g(const GW& g, const float* base1,
                                          const float* base2, float* hbl, int t,
                                          int vc, int vr0, int gx0, int gy0,
                                          float (&l1s)[2]) {
  constexpr int QS = 0;
  constexpr int NG = ((19 + R) >> 2) + 1;
  __syncthreads();                  // prior v-reads of hb done
  {
    const int hrow = t >> 3;
    const int cg = t & 7;
    const int gy = gy0 + hrow;      // 16-R == 0
    float a0[4] = {0.f, 0.f, 0.f, 0.f};
    if (gy >= 0 && gy < 512) {
      const size_t rowoff = (size_t)gy << 9;
      const int c0 = gx0 + (cg << 2);
#pragma unroll 2
      for (int j = 0; j < NG; ++j) {
        const int cx = c0 + (j << 2);
        float4 av[3], bv[3];
#pragma unroll
        for (int ch = 0; ch < 3; ++ch) {
          const float* r1 = base1 + ((size_t)ch << 18) + rowoff;
          const float* r2 = base2 + ((size_t)ch << 18) + rowoff;
          if constexpr (EX) { av[ch] = ld4_guard(r1, cx); bv[ch] = ld4_guard(r2, cx); }
          else { av[ch] = *reinterpret_cast<const float4*>(r1 + cx);
                 bv[ch] = *reinterpret_cast<const float4*>(r2 + cx); }
        }
        const int wb = WOFF + 8 + QS - 16 + R + 4 * j;
#pragma unroll
        for (int u = 0; u < 4; ++u) {
          float sum = 0.f;
#pragma unroll
          for (int ch = 0; ch < 3; ++ch) {
            const float* ap = reinterpret_cast<const float*>(&av[ch]);
            const float* bp = reinterpret_cast<const float*>(&bv[ch]);
            sum += fabsf(ap[u] - bp[u]);
          }
#pragma unroll
          for (int o = 0; o < 4; ++o) a0[o] += g.w[wb + u - o] * sum;
        }
      }
    }
    *reinterpret_cast<float4*>(&hbl[(hrow << 5) + (cg << 2)]) =
        make_float4(a0[0], a0[1], a0[2], a0[3]);
  }
  __syncthreads();
  const float* __restrict__ hblp = hbl + (vr0 << 5) + vc;
#pragma unroll 4
  for (int jj = 0; jj < 2 * R + 2; ++jj) {
    const float vl = hblp[jj << 5];
    const int wb = WOFF + 8 + jj;
#pragma unroll
    for (int i = 0; i < 2; ++i) l1s[i] += g.w[wb - i] * vl;
  }
}

template<bool EX>
__device__ __forceinline__ void run_all(const GW& g, const float* base1,
                                        const float* base2, float4* hb, int t,
                                        int vc, int vr0, int gx0, int gy0,
                                        float (&PI)[2], float (&lM)[2],
                                        float (&l1s)[2]) {
  const float* c0a = base1;                const float* c0b = base2;
  const float* c1a = base1 + (1 << 18);    const float* c1b = base2 + (1 << 18);
  const float* c2a = base1 + (2 << 18);    const float* c2b = base2 + (2 << 18);
  // Channel 0: cs(s0.5)^3 * cs(s1)^2
  sweep4<2, W05, 3, false, EX>(g, c0a, c0b, hb, t, vc, vr0, gx0, gy0, PI, lM);
  sweep4<4, W1, 2, false, EX>(g, c0a, c0b, hb, t, vc, vr0, gx0, gy0, PI, lM);
  // Channel 1: cs(s1)^1 * cs(s2)^3 * cs(s4)^1
  sweep4<4, W1, 1, false, EX>(g, c1a, c1b, hb, t, vc, vr0, gx0, gy0, PI, lM);
  sweep4<9, W2, 3, false, EX>(g, c1a, c1b, hb, t, vc, vr0, gx0, gy0, PI, lM);
  sweep4<12, W4, 1, false, EX>(g, c1a, c1b, hb, t, vc, vr0, gx0, gy0, PI, lM);
  // Channel 2: cs(s4)^2 * cs(s8)^3 + lM(s8)
  sweep4<12, W4, 2, false, EX>(g, c2a, c2b, hb, t, vc, vr0, gx0, gy0, PI, lM);
  sweep4<16, W8, 3, true, EX>(g, c2a, c2b, hb, t, vc, vr0, gx0, gy0, PI, lM);
  // Fused L1: one sigma-8 blur of sum_ch |x-y|.
  sweepL1_g<16, W8, EX>(g, base1, base2, reinterpret_cast<float*>(hb), t,
                        vc, vr0, gx0, gy0, l1s);
}

}  // namespace

extern "C" __global__ __launch_bounds__(512, 8) void msssim_main(
    const float* __restrict__ img1, const float* __restrict__ img2,
    float* __restrict__ partial, GW g) {
  __shared__ __align__(16) float4 hb[2048];   // 32 KB; L1 aliases first 8 KB
  __shared__ float red[8];

  const int t = threadIdx.x;

  // XCD-contiguous swizzle: 2048 blocks / 8 XCDs -> XCD k owns batch image k.
  const int bid = (int)blockIdx.x + ((int)blockIdx.y << 4) + ((int)blockIdx.z << 8);
  const int swz = ((bid & 7) << 8) + (bid >> 3);
  const int bx = swz & 15, by = (swz >> 4) & 15, b = swz >> 8;

  const int gx0 = bx * 32 - 16;
  const int gy0 = by * 32 - 16;
  const int vc = t & 31;          // owned column
  const int vr0 = (t >> 5) << 1;  // owned row base (2 consecutive rows)

  float PI[2] = {1.f, 1.f};
  float lM[2] = {0.f, 0.f};
  float l1s[2] = {0.f, 0.f};

  const float* base1 = img1 + ((size_t)b * 3 << 18);
  const float* base2 = img2 + ((size_t)b * 3 << 18);

  if (bx == 0 || bx == 15) {
    run_all<true>(g, base1, base2, hb, t, vc, vr0, gx0, gy0, PI, lM, l1s);
  } else {
    run_all<false>(g, base1, base2, hb, t, vc, vr0, gx0, gy0, PI, lM, l1s);
  }

  float s = 0.f;
#pragma unroll
  for (int i = 0; i < 2; ++i)
    s += 0.025f * (1.f - lM[i] * PI[i]) + 0.975f * (l1s[i] * (1.f / 3.f));

#pragma unroll
  for (int off = 32; off >= 1; off >>= 1) s += __shfl_down(s, off, 64);
  if ((t & 63) == 0) red[t >> 6] = s;
  __syncthreads();
  if (t == 0) {
    float tot = 0.f;
#pragma unroll
    for (int i = 0; i < 8; ++i) tot += red[i];
    partial[swz] = tot;
  }
}

extern "C" __global__ __launch_bounds__(256) void msssim_reduce(
    const float* __restrict__ partial, float* __restrict__ out, int n) {
  __shared__ float red[4];
  float s = 0.f;
  for (int i = threadIdx.x; i < n; i += 256) s += partial[i];
#pragma unroll
  for (int off = 32; off >= 1; off >>= 1) s += __shfl_down(s, off, 64);
  if ((threadIdx.x & 63) == 0) red[threadIdx.x >> 6] = s;
  __syncthreads();
  if (threadIdx.x == 0) {
    out[0] = (red[0] + red[1] + red[2] + red[3]) * (200.0f / 2097152.0f);
  }
}

extern "C" void kernel_launch(void* const* d_in, const int* in_sizes, int n_in,
                              void* d_out, int out_size, void* d_ws, size_t ws_size,
                              hipStream_t stream) {
  const float* img1 = (const float*)d_in[0];
  const float* img2 = (const float*)d_in[1];
  float* out = (float*)d_out;
  float* partial = (float*)d_ws;  // 2048 floats

  // Host-side padded weight tables (double-precision normalize over 2R+1 taps).
  GW g;
  {
    const double sig[5] = {0.5, 1.0, 2.0, 4.0, 8.0};
    const int R[5] = {2, 4, 9, 12, 16};
    const int off[5] = {W05, W1, W2, W4, W8};
    for (int i = 0; i < 5; ++i) {
      double tmp[17];
      double sum = 0.0;
      for (int k = 0; k <= R[i]; ++k) {
        tmp[k] = exp(-(double)(k * k) / (2.0 * sig[i] * sig[i]));
        sum += (k ? 2.0 : 1.0) * tmp[k];
      }
      const int len = 2 * R[i] + 17;
      for (int m = 0; m < len; ++m) {
        int d = m - 8 - R[i];
        if (d < 0) d = -d;
        g.w[off[i] + m] = (m >= 8 && m <= 8 + 2 * R[i]) ? (float)(tmp[d] / sum) : 0.0f;
      }
    }
  }

  dim3 grid(16, 16, 8);
  msssim_main<<<grid, dim3(512), 0, stream>>>(img1, img2, partial, g);
  msssim_reduce<<<1, dim3(256), 0, stream>>>(partial, out, 2048);
}

// Round 15
// 216.675 us; speedup vs baseline: 1.6729x; 1.6729x over previous
//
#include <hip/hip_runtime.h>
#include <math.h>

// Zero-padded symmetric weight tables (fp32, kernarg): per sigma,
// [8 zeros][w[R],...,w[1],w[0],w[1],...,w[R]][8 zeros]  (length 2R+17).
// Truncation (renormalized): sigma1 R4 / sigma2 R9 tails ~1e-6;
// sigma4 R12 tail ~0.17% (cancels in cs/lc ratios); sigma8 R16 exact.
struct GW { float w[171]; };
constexpr int W05 = 0;    // sigma 0.5, R=2
constexpr int W1  = 21;   // sigma 1,   R=4
constexpr int W2  = 46;   // sigma 2,   R=9
constexpr int W4  = 81;   // sigma 4,   R=12
constexpr int W8  = 122;  // sigma 8,   R=16

namespace {

constexpr float kC1 = 1e-4f;
constexpr float kC2 = 9e-4f;

// 512 threads/block, 32x32 output tile. LDS = hb only (32.3 KB).
// h-pass reads img1/img2 rows DIRECTLY from global (coalesced, L2/L3-served);
// s=x+y, d=x-y computed on the fly. No input tiles in LDS at all.
//  hb : [<=64 rows][32 slots] float4 (s,d,s2,d2), slot c^((c>>3)&3), 32 KB.
//  L1 reuse of hb: [64][32] floats, plain layout (8 KB).
// launch_bounds (512,4): VGPR cap 128 (no spill), >=16 waves/CU.

__device__ __forceinline__ float4 ld4_guard(const float* __restrict__ row, int cx) {
  // Column-guarded float4 load (edge blocks only).
  if (cx >= 0 && cx + 3 < 512) return *reinterpret_cast<const float4*>(row + cx);
  float4 v = make_float4(0.f, 0.f, 0.f, 0.f);
  float* vp = reinterpret_cast<float*>(&v);
#pragma unroll
  for (int u = 0; u < 4; ++u) {
    const int x = cx + u;
    if (x >= 0 && x < 512) vp[u] = row[x];
  }
  return v;
}

// Horizontal pass from GLOBAL, rows trimmed to NROWS=32+2R. One entry/thread.
template<int R, int WOFF, bool EX>
__device__ __forceinline__ void hpass_g(const GW& g, const float* __restrict__ p1,
                                        const float* __restrict__ p2,
                                        float4* __restrict__ hb, int t,
                                        int gx0, int gy0) {
  constexpr int NROWS = 32 + 2 * R;
  constexpr int NE = NROWS * 8;
  constexpr int QS = (16 - R) & ~3;
  constexpr int NG = ((19 + R - QS) >> 2) + 1;
  if (t >= NE) return;
  const int hrow = t >> 3;
  const int cg = t & 7;
  const int gy = gy0 + hrow + (16 - R);
  float a0[4] = {0.f, 0.f, 0.f, 0.f}, a1[4] = {0.f, 0.f, 0.f, 0.f};
  float a2[4] = {0.f, 0.f, 0.f, 0.f}, a3[4] = {0.f, 0.f, 0.f, 0.f};
  if (gy >= 0 && gy < 512) {
    const float* __restrict__ r1 = p1 + ((size_t)gy << 9);
    const float* __restrict__ r2 = p2 + ((size_t)gy << 9);
    const int c0 = gx0 + ((cg + (QS >> 2)) << 2);
#pragma unroll 2
    for (int j = 0; j < NG; ++j) {
      const int cx = c0 + (j << 2);
      float4 a, bb;
      if constexpr (EX) { a = ld4_guard(r1, cx); bb = ld4_guard(r2, cx); }
      else { a = *reinterpret_cast<const float4*>(r1 + cx);
             bb = *reinterpret_cast<const float4*>(r2 + cx); }
      const int wb = WOFF + 8 + QS - 16 + R + 4 * j;  // + u - o; pads absorb
      const float* ap = reinterpret_cast<const float*>(&a);
      const float* bp = reinterpret_cast<const float*>(&bb);
#pragma unroll
      for (int u = 0; u < 4; ++u) {
        const float sv = ap[u] + bp[u];
        const float dv = ap[u] - bp[u];
        const float s2 = sv * sv, d2 = dv * dv;
#pragma unroll
        for (int o = 0; o < 4; ++o) {
          const float wk = g.w[wb + u - o];
          a0[o] += wk * sv; a1[o] += wk * dv;
          a2[o] += wk * s2; a3[o] += wk * d2;
        }
      }
    }
  }
  const int rb = hrow << 5;
#pragma unroll
  for (int o = 0; o < 4; ++o) {
    const int c = (cg << 2) + o;
    hb[rb + (c ^ ((c >> 3) & 3))] = make_float4(a0[o], a1[o], a2[o], a3[o]);
  }
}

// Vertical pass. Thread owns col vc, rows vr0..vr0+1.
template<int R, int WOFF>
__device__ __forceinline__ void vpass4(const GW& g, const float4* __restrict__ hb,
                                       int vc, int vr0,
                                       float (&o0)[2], float (&o1)[2],
                                       float (&o2)[2], float (&o3)[2]) {
#pragma unroll
  for (int i = 0; i < 2; ++i) { o0[i] = o1[i] = o2[i] = o3[i] = 0.f; }
  const int fc = vc ^ ((vc >> 3) & 3);
  const float4* __restrict__ hbp = hb + (vr0 << 5) + fc;
#pragma unroll 4
  for (int jj = 0; jj < 2 * R + 2; ++jj) {
    const float4 v = hbp[jj << 5];
    const int wb = WOFF + 8 + jj;
#pragma unroll
    for (int i = 0; i < 2; ++i) {
      const float wk = g.w[wb - i];
      o0[i] += wk * v.x; o1[i] += wk * v.y;
      o2[i] += wk * v.z; o3[i] += wk * v.w;
    }
  }
}

template<int R, int WOFF, int MULT, bool DOLM, bool EX>
__device__ __forceinline__ void sweep4(const GW& g, const float* p1, const float* p2,
                                       float4* hb, int t, int vc, int vr0,
                                       int gx0, int gy0,
                                       float (&PI)[2], float (&lM)[2]) {
  __syncthreads();                  // prior v-reads of hb done
  hpass_g<R, WOFF, EX>(g, p1, p2, hb, t, gx0, gy0);
  __syncthreads();
  float os[2], od[2], os2[2], od2[2];
  vpass4<R, WOFF>(g, hb, vc, vr0, os, od, os2, od2);
#pragma unroll
  for (int i = 0; i < 2; ++i) {
    const float vs = os2[i] - os[i] * os[i];   // Var(x+y)
    const float vd = od2[i] - od[i] * od[i];   // Var(x-y)
    const float cs = (0.5f * (vs - vd) + kC2) / (0.5f * (vs + vd) + kC2);
    float p = cs;
    if constexpr (MULT > 1) p *= cs;
    if constexpr (MULT > 2) p *= cs;
    PI[i] *= p;
    if constexpr (DOLM) {
      const float sa = os[i] * os[i], sb = od[i] * od[i];
      const float lc = (0.5f * (sa - sb) + kC1) / (0.5f * (sa + sb) + kC1);
      lM[i] = lc * lc * lc;
    }
  }
}

// Fused L1 (sigma 8, R=16): h-pass reads all 3 channels of both images from
// global, blurs sum_ch |x-y| (linearity of conv); then v-pass. hbl = hb alias.
template<int R, int WOFF, bool EX>
__device__ __forceinline__ void sweepL1_g(const GW& g, const float* base1,
                                          const float* base2, float* hbl, int t,
                                          int vc, int vr0, int gx0, int gy0,
                                          float (&l1s)[2]) {
  constexpr int QS = 0;
  constexpr int NG = ((19 + R) >> 2) + 1;
  __syncthreads();                  // prior v-reads of hb done
  {
    const int hrow = t >> 3;
    const int cg = t & 7;
    const int gy = gy0 + hrow;      // 16-R == 0
    float a0[4] = {0.f, 0.f, 0.f, 0.f};
    if (gy >= 0 && gy < 512) {
      const size_t rowoff = (size_t)gy << 9;
      const int c0 = gx0 + (cg << 2);
#pragma unroll 2
      for (int j = 0; j < NG; ++j) {
        const int cx = c0 + (j << 2);
        const int wb = WOFF + 8 + QS - 16 + R + 4 * j;
        float sum[4] = {0.f, 0.f, 0.f, 0.f};
#pragma unroll
        for (int ch = 0; ch < 3; ++ch) {
          const float* r1 = base1 + ((size_t)ch << 18) + rowoff;
          const float* r2 = base2 + ((size_t)ch << 18) + rowoff;
          float4 a, bb;
          if constexpr (EX) { a = ld4_guard(r1, cx); bb = ld4_guard(r2, cx); }
          else { a = *reinterpret_cast<const float4*>(r1 + cx);
                 bb = *reinterpret_cast<const float4*>(r2 + cx); }
          const float* ap = reinterpret_cast<const float*>(&a);
          const float* bp = reinterpret_cast<const float*>(&bb);
#pragma unroll
          for (int u = 0; u < 4; ++u) sum[u] += fabsf(ap[u] - bp[u]);
        }
#pragma unroll
        for (int u = 0; u < 4; ++u) {
#pragma unroll
          for (int o = 0; o < 4; ++o) a0[o] += g.w[wb + u - o] * sum[u];
        }
      }
    }
    *reinterpret_cast<float4*>(&hbl[(hrow << 5) + (cg << 2)]) =
        make_float4(a0[0], a0[1], a0[2], a0[3]);
  }
  __syncthreads();
  const float* __restrict__ hblp = hbl + (vr0 << 5) + vc;
#pragma unroll 4
  for (int jj = 0; jj < 2 * R + 2; ++jj) {
    const float vl = hblp[jj << 5];
    const int wb = WOFF + 8 + jj;
#pragma unroll
    for (int i = 0; i < 2; ++i) l1s[i] += g.w[wb - i] * vl;
  }
}

template<bool EX>
__device__ __forceinline__ void run_all(const GW& g, const float* base1,
                                        const float* base2, float4* hb, int t,
                                        int vc, int vr0, int gx0, int gy0,
                                        float (&PI)[2], float (&lM)[2],
                                        float (&l1s)[2]) {
  const float* c0a = base1;                const float* c0b = base2;
  const float* c1a = base1 + (1 << 18);    const float* c1b = base2 + (1 << 18);
  const float* c2a = base1 + (2 << 18);    const float* c2b = base2 + (2 << 18);
  // Channel 0: cs(s0.5)^3 * cs(s1)^2
  sweep4<2, W05, 3, false, EX>(g, c0a, c0b, hb, t, vc, vr0, gx0, gy0, PI, lM);
  sweep4<4, W1, 2, false, EX>(g, c0a, c0b, hb, t, vc, vr0, gx0, gy0, PI, lM);
  // Channel 1: cs(s1)^1 * cs(s2)^3 * cs(s4)^1
  sweep4<4, W1, 1, false, EX>(g, c1a, c1b, hb, t, vc, vr0, gx0, gy0, PI, lM);
  sweep4<9, W2, 3, false, EX>(g, c1a, c1b, hb, t, vc, vr0, gx0, gy0, PI, lM);
  sweep4<12, W4, 1, false, EX>(g, c1a, c1b, hb, t, vc, vr0, gx0, gy0, PI, lM);
  // Channel 2: cs(s4)^2 * cs(s8)^3 + lM(s8)
  sweep4<12, W4, 2, false, EX>(g, c2a, c2b, hb, t, vc, vr0, gx0, gy0, PI, lM);
  sweep4<16, W8, 3, true, EX>(g, c2a, c2b, hb, t, vc, vr0, gx0, gy0, PI, lM);
  // Fused L1: one sigma-8 blur of sum_ch |x-y|.
  sweepL1_g<16, W8, EX>(g, base1, base2, reinterpret_cast<float*>(hb), t,
                        vc, vr0, gx0, gy0, l1s);
}

}  // namespace

extern "C" __global__ __launch_bounds__(512, 4) void msssim_main(
    const float* __restrict__ img1, const float* __restrict__ img2,
    float* __restrict__ partial, GW g) {
  __shared__ __align__(16) float4 hb[2048];   // 32 KB; L1 aliases first 8 KB
  __shared__ float red[8];

  const int t = threadIdx.x;

  // XCD-contiguous swizzle: 2048 blocks / 8 XCDs -> XCD k owns batch image k.
  const int bid = (int)blockIdx.x + ((int)blockIdx.y << 4) + ((int)blockIdx.z << 8);
  const int swz = ((bid & 7) << 8) + (bid >> 3);
  const int bx = swz & 15, by = (swz >> 4) & 15, b = swz >> 8;

  const int gx0 = bx * 32 - 16;
  const int gy0 = by * 32 - 16;
  const int vc = t & 31;          // owned column
  const int vr0 = (t >> 5) << 1;  // owned row base (2 consecutive rows)

  float PI[2] = {1.f, 1.f};
  float lM[2] = {0.f, 0.f};
  float l1s[2] = {0.f, 0.f};

  const float* base1 = img1 + ((size_t)b * 3 << 18);
  const float* base2 = img2 + ((size_t)b * 3 << 18);

  if (bx == 0 || bx == 15) {
    run_all<true>(g, base1, base2, hb, t, vc, vr0, gx0, gy0, PI, lM, l1s);
  } else {
    run_all<false>(g, base1, base2, hb, t, vc, vr0, gx0, gy0, PI, lM, l1s);
  }

  float s = 0.f;
#pragma unroll
  for (int i = 0; i < 2; ++i)
    s += 0.025f * (1.f - lM[i] * PI[i]) + 0.975f * (l1s[i] * (1.f / 3.f));

#pragma unroll
  for (int off = 32; off >= 1; off >>= 1) s += __shfl_down(s, off, 64);
  if ((t & 63) == 0) red[t >> 6] = s;
  __syncthreads();
  if (t == 0) {
    float tot = 0.f;
#pragma unroll
    for (int i = 0; i < 8; ++i) tot += red[i];
    partial[swz] = tot;
  }
}

extern "C" __global__ __launch_bounds__(256) void msssim_reduce(
    const float* __restrict__ partial, float* __restrict__ out, int n) {
  __shared__ float red[4];
  float s = 0.f;
  for (int i = threadIdx.x; i < n; i += 256) s += partial[i];
#pragma unroll
  for (int off = 32; off >= 1; off >>= 1) s += __shfl_down(s, off, 64);
  if ((threadIdx.x & 63) == 0) red[threadIdx.x >> 6] = s;
  __syncthreads();
  if (threadIdx.x == 0) {
    out[0] = (red[0] + red[1] + red[2] + red[3]) * (200.0f / 2097152.0f);
  }
}

extern "C" void kernel_launch(void* const* d_in, const int* in_sizes, int n_in,
                              void* d_out, int out_size, void* d_ws, size_t ws_size,
                              hipStream_t stream) {
  const float* img1 = (const float*)d_in[0];
  const float* img2 = (const float*)d_in[1];
  float* out = (float*)d_out;
  float* partial = (float*)d_ws;  // 2048 floats

  // Host-side padded weight tables (double-precision normalize over 2R+1 taps).
  GW g;
  {
    const double sig[5] = {0.5, 1.0, 2.0, 4.0, 8.0};
    const int R[5] = {2, 4, 9, 12, 16};
    const int off[5] = {W05, W1, W2, W4, W8};
    for (int i = 0; i < 5; ++i) {
      double tmp[17];
      double sum = 0.0;
      for (int k = 0; k <= R[i]; ++k) {
        tmp[k] = exp(-(double)(k * k) / (2.0 * sig[i] * sig[i]));
        sum += (k ? 2.0 : 1.0) * tmp[k];
      }
      const int len = 2 * R[i] + 17;
      for (int m = 0; m < len; ++m) {
        int d = m - 8 - R[i];
        if (d < 0) d = -d;
        g.w[off[i] + m] = (m >= 8 && m <= 8 + 2 * R[i]) ? (float)(tmp[d] / sum) : 0.0f;
      }
    }
  }

  dim3 grid(16, 16, 8);
  msssim_main<<<grid, dim3(512), 0, stream>>>(img1, img2, partial, g);
  msssim_reduce<<<1, dim3(256), 0, stream>>>(partial, out, 2048);
}

// Round 16
// 129.654 us; speedup vs baseline: 2.7958x; 1.6712x over previous
//
#include <hip/hip_runtime.h>
#include <math.h>

// CHAMPION (round 9/10 structure) — reverted after r11-r15 structural
// experiments all regressed. 129 us timed / ~141 us dispatch.
//
// Zero-padded symmetric weight tables: per sigma, layout is
// [8 zeros][w[R], ..., w[1], w[0], w[1], ..., w[R]][8 zeros]  (length 2R+17).
// Index m in [0, 2R] holds w[|m-R|] at table offset m+8. The pads absorb all
// out-of-range taps so the tap loops need no conditionals.
// Truncation (renormalized): sigma1 R4 / sigma2 R9 tails ~1e-6 (exact-ish);
// sigma4 R12 tail mass ~0.17% (largely cancels in cs/lc ratios);
// sigma8 R16 exact (also keeps the L1 path exact).
struct GW { float w[171]; };
constexpr int W05 = 0;    // sigma 0.5, R=2,  len 21
constexpr int W1  = 21;   // sigma 1,   R=4,  len 25
constexpr int W2  = 46;   // sigma 2,   R=9,  len 35
constexpr int W4  = 81;   // sigma 4,   R=12, len 41
constexpr int W8  = 122;  // sigma 8,   R=16, len 49

namespace {

constexpr float kC1 = 1e-4f;
constexpr float kC2 = 9e-4f;

// 512 threads/block, 32x32 output tile.
// LDS (64.5 KB -> 2 blocks/CU = 16 waves/CU):
//  sS/sD : [64][64] floats, float4-group g XOR'd by (row&7)   (16 KB each)
//  hb4   : [<=64 rows][32 slots] float4 (s,d,s2,d2), slot c^((c>>3)&3) (32 KB)
//  hbl   : L1 reuse of hb4: [64][32] floats, plain layout (8 KB).
// L1 fusion: blur is linear -> mean_ch blur(|d_ch|) = blur(sum_ch |d_ch|)/3.

// Horizontal pass, rows trimmed to NROWS=32+2R (hrow h = halo row h+16-R).
// One entry per thread (NE = NROWS*8 <= 512).
template<int R, int WOFF>
__device__ __forceinline__ void hpass4(const GW& g, const float* __restrict__ sS,
                                       const float* __restrict__ sD,
                                       float4* __restrict__ hb, int t) {
  constexpr int NROWS = 32 + 2 * R;
  constexpr int NE = NROWS * 8;
  constexpr int QS = (16 - R) & ~3;
  constexpr int NG = ((19 + R - QS) >> 2) + 1;
  if (t >= NE) return;
  const int hrow = t >> 3;
  const int cg = t & 7;
  const int srow = hrow + (16 - R);
  const int rx = srow & 7;
  const int rowbase = srow << 6;
  const int g0 = cg + (QS >> 2);
  float a0[4] = {0.f, 0.f, 0.f, 0.f}, a1[4] = {0.f, 0.f, 0.f, 0.f};
  float a2[4] = {0.f, 0.f, 0.f, 0.f}, a3[4] = {0.f, 0.f, 0.f, 0.f};
#pragma unroll 2
  for (int j = 0; j < NG; ++j) {
    const int off = rowbase + (((g0 + j) ^ rx) << 2);
    const int wb = WOFF + 8 + QS - 16 + R + 4 * j;  // + u - o; pads absorb ends
    const float4 s4 = *reinterpret_cast<const float4*>(&sS[off]);
    const float4 d4 = *reinterpret_cast<const float4*>(&sD[off]);
    const float* sp = reinterpret_cast<const float*>(&s4);
    const float* dp = reinterpret_cast<const float*>(&d4);
#pragma unroll
    for (int u = 0; u < 4; ++u) {
      const float sv = sp[u], dv = dp[u];
      const float s2 = sv * sv, d2 = dv * dv;
#pragma unroll
      for (int o = 0; o < 4; ++o) {
        const float wk = g.w[wb + u - o];
        a0[o] += wk * sv; a1[o] += wk * dv;
        a2[o] += wk * s2; a3[o] += wk * d2;
      }
    }
  }
  const int rb = hrow << 5;
#pragma unroll
  for (int o = 0; o < 4; ++o) {
    const int c = (cg << 2) + o;
    hb[rb + (c ^ ((c >> 3) & 3))] = make_float4(a0[o], a1[o], a2[o], a3[o]);
  }
}

// Vertical pass. Thread owns col vc = t&31, output rows vr0..vr0+1.
template<int R, int WOFF>
__device__ __forceinline__ void vpass4(const GW& g, const float4* __restrict__ hb,
                                       int vc, int vr0,
                                       float (&o0)[2], float (&o1)[2],
                                       float (&o2)[2], float (&o3)[2]) {
#pragma unroll
  for (int i = 0; i < 2; ++i) { o0[i] = o1[i] = o2[i] = o3[i] = 0.f; }
  const int fc = vc ^ ((vc >> 3) & 3);
  const float4* __restrict__ hbp = hb + (vr0 << 5) + fc;
#pragma unroll 4
  for (int jj = 0; jj < 2 * R + 2; ++jj) {
    const float4 v = hbp[jj << 5];
    const int wb = WOFF + 8 + jj;   // weight index: wb - i; pads absorb ends
#pragma unroll
    for (int i = 0; i < 2; ++i) {
      const float wk = g.w[wb - i];
      o0[i] += wk * v.x; o1[i] += wk * v.y;
      o2[i] += wk * v.z; o3[i] += wk * v.w;
    }
  }
}

template<int R, int WOFF, int MULT, bool DOLM>
__device__ __forceinline__ void sweep4(const GW& g,
    const float* sS, const float* sD, float4* hb, int t, int vc, int vr0,
    float (&PI)[2], float (&lM)[2]) {
  __syncthreads();                  // hb free, tile visible
  hpass4<R, WOFF>(g, sS, sD, hb, t);
  __syncthreads();
  float os[2], od[2], os2[2], od2[2];
  vpass4<R, WOFF>(g, hb, vc, vr0, os, od, os2, od2);
#pragma unroll
  for (int i = 0; i < 2; ++i) {
    const float vs = os2[i] - os[i] * os[i];   // Var(x+y)
    const float vd = od2[i] - od[i] * od[i];   // Var(x-y)
    const float cs = (0.5f * (vs - vd) + kC2) / (0.5f * (vs + vd) + kC2);
    float p = cs;
    if constexpr (MULT > 1) p *= cs;
    if constexpr (MULT > 2) p *= cs;
    PI[i] *= p;
    if constexpr (DOLM) {
      const float sa = os[i] * os[i], sb = od[i] * od[i];
      const float lc = (0.5f * (sa - sb) + kC1) / (0.5f * (sa + sb) + kC1);
      lM[i] = lc * lc * lc;
    }
  }
}

// L1 h-pass (sigma 8, R=16): blur of the pre-summed |d| tile in sD.
template<int R, int WOFF>
__device__ __forceinline__ void hpassL1(const GW& g, const float* __restrict__ sD,
                                        float* __restrict__ hbl, int t) {
  constexpr int QS = (16 - R) & ~3;
  constexpr int NG = ((19 + R - QS) >> 2) + 1;
  const int hrow = t >> 3;
  const int cg = t & 7;
  const int rx = hrow & 7;           // srow == hrow for R=16
  const int rowbase = hrow << 6;
  const int g0 = cg + (QS >> 2);
  float a0[4] = {0.f, 0.f, 0.f, 0.f};
#pragma unroll 2
  for (int j = 0; j < NG; ++j) {
    const int off = rowbase + (((g0 + j) ^ rx) << 2);
    const int wb = WOFF + 8 + QS - 16 + R + 4 * j;
    const float4 d4 = *reinterpret_cast<const float4*>(&sD[off]);
    const float* dp = reinterpret_cast<const float*>(&d4);
#pragma unroll
    for (int u = 0; u < 4; ++u) {
      const float av = dp[u];        // already >= 0 (sum of |d|)
#pragma unroll
      for (int o = 0; o < 4; ++o) a0[o] += g.w[wb + u - o] * av;
    }
  }
  *reinterpret_cast<float4*>(&hbl[(hrow << 5) + (cg << 2)]) =
      make_float4(a0[0], a0[1], a0[2], a0[3]);
}

// Fused L1 sweep: dump register-accumulated sum_ch |d| into sD (dead after the
// last hpass4), then one sigma-8 blur.
template<int R, int WOFF>
__device__ __forceinline__ void sweepL1_fused(const GW& g, float* sD, float* hbl,
                                              const float (&al1)[8], int t,
                                              int vc, int vr0, float (&l1s)[2]) {
#pragma unroll
  for (int e = 0; e < 2; ++e) {
    const int gidx = t + (e << 9);
    const int ly = gidx >> 4, lg = gidx & 15;
    const int off = (ly << 6) + ((lg ^ (ly & 7)) << 2);
    *reinterpret_cast<float4*>(&sD[off]) =
        make_float4(al1[4 * e], al1[4 * e + 1], al1[4 * e + 2], al1[4 * e + 3]);
  }
  __syncthreads();
  hpassL1<R, WOFF>(g, sD, hbl, t);
  __syncthreads();
  const float* __restrict__ hblp = hbl + (vr0 << 5) + vc;
#pragma unroll 4
  for (int jj = 0; jj < 2 * R + 2; ++jj) {
    const float vl = hblp[jj << 5];
    const int wb = WOFF + 8 + jj;
#pragma unroll
    for (int i = 0; i < 2; ++i) l1s[i] += g.w[wb - i] * vl;
  }
}

__device__ __forceinline__ void load_tile(const float* __restrict__ p1,
                                          const float* __restrict__ p2,
                                          float* __restrict__ sS, float* __restrict__ sD,
                                          float (&al1)[8], int t, int gx0, int gy0) {
#pragma unroll 1
  for (int e = 0; e < 2; ++e) {
    const int gidx = t + (e << 9);
    const int ly = gidx >> 4, lg = gidx & 15;
    const int gy = gy0 + ly;
    const int gx = gx0 + (lg << 2);
    float4 a = make_float4(0.f, 0.f, 0.f, 0.f);
    float4 b = make_float4(0.f, 0.f, 0.f, 0.f);
    if (gy >= 0 && gy < 512) {
      if (gx >= 0 && gx + 3 < 512) {
        a = *reinterpret_cast<const float4*>(&p1[(gy << 9) + gx]);
        b = *reinterpret_cast<const float4*>(&p2[(gy << 9) + gx]);
      } else {
        float* ap = reinterpret_cast<float*>(&a);
        float* bp = reinterpret_cast<float*>(&b);
#pragma unroll
        for (int u = 0; u < 4; ++u) {
          const int x = gx + u;
          if (x >= 0 && x < 512) { ap[u] = p1[(gy << 9) + x]; bp[u] = p2[(gy << 9) + x]; }
        }
      }
    }
    float4 s, d;
    s.x = a.x + b.x; s.y = a.y + b.y; s.z = a.z + b.z; s.w = a.w + b.w;
    d.x = a.x - b.x; d.y = a.y - b.y; d.z = a.z - b.z; d.w = a.w - b.w;
    al1[4 * e + 0] += fabsf(d.x); al1[4 * e + 1] += fabsf(d.y);
    al1[4 * e + 2] += fabsf(d.z); al1[4 * e + 3] += fabsf(d.w);
    const int off = (ly << 6) + ((lg ^ (ly & 7)) << 2);
    *reinterpret_cast<float4*>(&sS[off]) = s;
    *reinterpret_cast<float4*>(&sD[off]) = d;
  }
}

}  // namespace

extern "C" __global__ __launch_bounds__(512) void msssim_main(
    const float* __restrict__ img1, const float* __restrict__ img2,
    float* __restrict__ partial, GW g) {
  __shared__ __align__(16) float sS[4096];
  __shared__ __align__(16) float sD[4096];
  __shared__ __align__(16) float4 hb[2048];   // 32 KB; L1 aliases first 8 KB
  __shared__ float red[8];
  float* hbl = reinterpret_cast<float*>(hb);

  const int t = threadIdx.x;

  // XCD-contiguous swizzle: 2048 blocks / 8 XCDs -> XCD k owns batch image k.
  const int bid = (int)blockIdx.x + ((int)blockIdx.y << 4) + ((int)blockIdx.z << 8);
  const int swz = ((bid & 7) << 8) + (bid >> 3);
  const int bx = swz & 15, by = (swz >> 4) & 15, b = swz >> 8;

  const int gx0 = bx * 32 - 16;
  const int gy0 = by * 32 - 16;
  const int vc = t & 31;          // owned column
  const int vr0 = (t >> 5) << 1;  // owned row base (2 consecutive rows)

  float PI[2] = {1.f, 1.f};
  float lM[2] = {0.f, 0.f};
  float l1s[2] = {0.f, 0.f};
  float al1[8] = {0.f, 0.f, 0.f, 0.f, 0.f, 0.f, 0.f, 0.f};

  // Channel 0: cs(s0.5)^3 * cs(s1)^2
  {
    const float* p1 = img1 + (((size_t)b * 3 + 0) << 18);
    const float* p2 = img2 + (((size_t)b * 3 + 0) << 18);
    load_tile(p1, p2, sS, sD, al1, t, gx0, gy0);
    sweep4<2, W05, 3, false>(g, sS, sD, hb, t, vc, vr0, PI, lM);
    sweep4<4, W1, 2, false>(g, sS, sD, hb, t, vc, vr0, PI, lM);
  }
  // Channel 1: cs(s1)^1 * cs(s2)^3 * cs(s4)^1
  {
    const float* p1 = img1 + (((size_t)b * 3 + 1) << 18);
    const float* p2 = img2 + (((size_t)b * 3 + 1) << 18);
    load_tile(p1, p2, sS, sD, al1, t, gx0, gy0);
    sweep4<4, W1, 1, false>(g, sS, sD, hb, t, vc, vr0, PI, lM);
    sweep4<9, W2, 3, false>(g, sS, sD, hb, t, vc, vr0, PI, lM);
    sweep4<12, W4, 1, false>(g, sS, sD, hb, t, vc, vr0, PI, lM);
  }
  // Channel 2: cs(s4)^2 * cs(s8)^3 + lM(s8)
  {
    const float* p1 = img1 + (((size_t)b * 3 + 2) << 18);
    const float* p2 = img2 + (((size_t)b * 3 + 2) << 18);
    load_tile(p1, p2, sS, sD, al1, t, gx0, gy0);
    sweep4<12, W4, 2, false>(g, sS, sD, hb, t, vc, vr0, PI, lM);
    sweep4<16, W8, 3, true>(g, sS, sD, hb, t, vc, vr0, PI, lM);
  }
  // Fused L1: one sigma-8 blur of sum_ch |d| (linearity of conv).
  sweepL1_fused<16, W8>(g, sD, hbl, al1, t, vc, vr0, l1s);

  float s = 0.f;
#pragma unroll
  for (int i = 0; i < 2; ++i)
    s += 0.025f * (1.f - lM[i] * PI[i]) + 0.975f * (l1s[i] * (1.f / 3.f));

#pragma unroll
  for (int off = 32; off >= 1; off >>= 1) s += __shfl_down(s, off, 64);
  if ((t & 63) == 0) red[t >> 6] = s;
  __syncthreads();
  if (t == 0) {
    float tot = 0.f;
#pragma unroll
    for (int i = 0; i < 8; ++i) tot += red[i];
    partial[swz] = tot;
  }
}

extern "C" __global__ __launch_bounds__(256) void msssim_reduce(
    const float* __restrict__ partial, float* __restrict__ out, int n) {
  __shared__ float red[4];
  float s = 0.f;
  for (int i = threadIdx.x; i < n; i += 256) s += partial[i];
#pragma unroll
  for (int off = 32; off >= 1; off >>= 1) s += __shfl_down(s, off, 64);
  if ((threadIdx.x & 63) == 0) red[threadIdx.x >> 6] = s;
  __syncthreads();
  if (threadIdx.x == 0) {
    out[0] = (red[0] + red[1] + red[2] + red[3]) * (200.0f / 2097152.0f);
  }
}

extern "C" void kernel_launch(void* const* d_in, const int* in_sizes, int n_in,
                              void* d_out, int out_size, void* d_ws, size_t ws_size,
                              hipStream_t stream) {
  const float* img1 = (const float*)d_in[0];
  const float* img2 = (const float*)d_in[1];
  float* out = (float*)d_out;
  float* partial = (float*)d_ws;  // 2048 floats

  // Host-side padded weight tables (double-precision normalize over 2R+1 taps).
  GW g;
  {
    const double sig[5] = {0.5, 1.0, 2.0, 4.0, 8.0};
    const int R[5] = {2, 4, 9, 12, 16};
    const int off[5] = {W05, W1, W2, W4, W8};
    for (int i = 0; i < 5; ++i) {
      double tmp[17];
      double sum = 0.0;
      for (int k = 0; k <= R[i]; ++k) {
        tmp[k] = exp(-(double)(k * k) / (2.0 * sig[i] * sig[i]));
        sum += (k ? 2.0 : 1.0) * tmp[k];
      }
      const int len = 2 * R[i] + 17;
      for (int m = 0; m < len; ++m) {
        int d = m - 8 - R[i];
        if (d < 0) d = -d;
        g.w[off[i] + m] = (m >= 8 && m <= 8 + 2 * R[i]) ? (float)(tmp[d] / sum) : 0.0f;
      }
    }
  }

  dim3 grid(16, 16, 8);
  msssim_main<<<grid, dim3(512), 0, stream>>>(img1, img2, partial, g);
  msssim_reduce<<<1, dim3(256), 0, stream>>>(partial, out, 2048);
}